// Round 4
// baseline (513.136 us; speedup 1.0000x reference)
//
#include <hip/hip_runtime.h>
#include <float.h>

// Problem constants: B=32 L=1024 D=128 K=1024
#define NTOK 32768
#define DDIM 128
#define KCODES 1024
#define TPB_TOK 64      // tokens per block == lanes per wave
#define PITCH 260       // words per dq-row (multiple of 4 -> 16B-aligned float4 slots)
#define CPW 256         // codes per wave (4 waves cover 1024)
#define CG 8            // codes per inner group (8 fp32 accumulators)

// Optimization barrier: blocks fma-contraction/reassociation so we replicate
// numpy's exact fp32 rounding sequence (argmin must match numpy bit-for-bit).
__device__ __forceinline__ float nofuse(float x) { asm volatile("" : "+v"(x)); return x; }

// ---------------- codebook norms, numpy pairwise order, LDS-coalesced -------
__global__ void cnorm_np(const float* __restrict__ cb, float* __restrict__ cnorm) {
    __shared__ float rows[64 * 129];     // [row][d], pitch 129 -> 2-way reads (free)
    const int tid = threadIdx.x;         // 0..63
    const int r0 = blockIdx.x * 64;
    #pragma unroll
    for (int it = 0; it < 32; ++it) {
        int g = it * 64 + tid;           // 0..2047 float4s
        int r = g >> 5, d4 = g & 31;
        float4 v = *(const float4*)(cb + (size_t)(r0 + r) * DDIM + 4 * d4);
        rows[r * 129 + 4 * d4 + 0] = v.x;
        rows[r * 129 + 4 * d4 + 1] = v.y;
        rows[r * 129 + 4 * d4 + 2] = v.z;
        rows[r * 129 + 4 * d4 + 3] = v.w;
    }
    __syncthreads();
    const float* p = &rows[tid * 129];
    float r[8];
    #pragma unroll
    for (int j = 0; j < 8; ++j) { float v = p[j]; r[j] = nofuse(v * v); }
    #pragma unroll
    for (int i = 8; i < DDIM; i += 8) {
        #pragma unroll
        for (int j = 0; j < 8; ++j) {
            float v = p[i + j];
            r[j] = nofuse(r[j] + nofuse(v * v));
        }
    }
    float s01 = nofuse(r[0] + r[1]);
    float s23 = nofuse(r[2] + r[3]);
    float s45 = nofuse(r[4] + r[5]);
    float s67 = nofuse(r[6] + r[7]);
    cnorm[r0 + tid] = nofuse(nofuse(s01 + s23) + nofuse(s45 + s67));
}

// ---------------- fused: distances + argmin + gather + loss + z_q -----------
// lane = token. Codebook side is wave-uniform -> scalar loads (K$ pipe),
// z side: 1 ds_read_b128 per lane feeds 32 FMA-instrs -> LDS no longer binding.
// dist(t,k) = fl( fl(zn_t + cn_k) - 2*dot ), dot accumulated fmaf d=0..127
// strictly ascending — bit-identical to the R3 kernel that passed.
__global__ __launch_bounds__(256, 4)
void vq_main(const float* __restrict__ z, const float* __restrict__ cb,
             const float* __restrict__ cnorm,
             float* __restrict__ zq, float* __restrict__ idxf,
             float* __restrict__ loss_accum) {
    __shared__ float zt[32 * PITCH];     // [dq][token*4], dq = d/4
    __shared__ float mv_s[4 * 64];
    __shared__ int   mi_s[4 * 64];

    const int tid  = threadIdx.x;
    const int lane = tid & 63;
    const int wv   = __builtin_amdgcn_readfirstlane(tid >> 6);  // force SGPR/uniform
    const int t0   = blockIdx.x * TPB_TOK;

    // ---- stage 64 tokens x 128 d, transposed-by-4: zt[dq][4*t .. 4*t+3] ----
    #pragma unroll
    for (int it = 0; it < 8; ++it) {
        int g = it * 256 + tid;          // 0..2047
        int r = g >> 5, d4 = g & 31;     // 32 lanes read one full 512B row: coalesced
        float4 v = *(const float4*)(z + (size_t)(t0 + r) * DDIM + 4 * d4);
        *(float4*)(&zt[d4 * PITCH + 4 * r]) = v;   // 16B-aligned (PITCH%4==0)
    }
    __syncthreads();

    // ---- per-lane zn in exact numpy pairwise order (from LDS) ----
    float zn;
    {
        float rr[8];
        float4 a = *(const float4*)(&zt[0 * PITCH + 4 * lane]);
        float4 b = *(const float4*)(&zt[1 * PITCH + 4 * lane]);
        float p0[8] = {a.x, a.y, a.z, a.w, b.x, b.y, b.z, b.w};
        #pragma unroll
        for (int j = 0; j < 8; ++j) rr[j] = nofuse(p0[j] * p0[j]);
        #pragma unroll
        for (int i = 1; i < 16; ++i) {
            float4 c = *(const float4*)(&zt[(2 * i) * PITCH + 4 * lane]);
            float4 d = *(const float4*)(&zt[(2 * i + 1) * PITCH + 4 * lane]);
            float q[8] = {c.x, c.y, c.z, c.w, d.x, d.y, d.z, d.w};
            #pragma unroll
            for (int j = 0; j < 8; ++j) rr[j] = nofuse(rr[j] + nofuse(q[j] * q[j]));
        }
        float s01 = nofuse(rr[0] + rr[1]);
        float s23 = nofuse(rr[2] + rr[3]);
        float s45 = nofuse(rr[4] + rr[5]);
        float s67 = nofuse(rr[6] + rr[7]);
        zn = nofuse(nofuse(s01 + s23) + nofuse(s45 + s67));
    }

    // ---- main loop: this wave's 256 codes in groups of 8 ----
    float minv = FLT_MAX;
    int   mini = 0;
    const int kw = wv * CPW;

    for (int cg = 0; cg < CPW / CG; ++cg) {
        const int kbase = kw + cg * CG;
        float cn[CG];
        #pragma unroll
        for (int c = 0; c < CG; ++c) cn[c] = cnorm[kbase + c];   // uniform -> s_load

        float acc[CG];
        #pragma unroll
        for (int c = 0; c < CG; ++c) acc[c] = 0.0f;

        #pragma unroll 4
        for (int ch = 0; ch < 32; ++ch) {                        // dq chunk = 4 d's
            float4 zv = *(const float4*)(&zt[ch * PITCH + 4 * lane]);
            #pragma unroll
            for (int c = 0; c < CG; ++c) {
                const float* bp = cb + (size_t)(kbase + c) * DDIM + 4 * ch;
                float b0 = bp[0], b1 = bp[1], b2 = bp[2], b3 = bp[3]; // uniform -> s_load_dwordx4
                acc[c] = fmaf(zv.x, b0, acc[c]);   // d ascending: 4ch+0..3
                acc[c] = fmaf(zv.y, b1, acc[c]);
                acc[c] = fmaf(zv.z, b2, acc[c]);
                acc[c] = fmaf(zv.w, b3, acc[c]);
            }
        }
        #pragma unroll
        for (int c = 0; c < CG; ++c) {
            float s = nofuse(zn + cn[c]);
            float dist = fmaf(-2.0f, acc[c], s);   // 2*acc exact (power of two)
            if (dist < minv) { minv = dist; mini = kbase + c; }  // strict <: lowest idx
        }
    }

    // ---- merge 4 waves (ascending code ranges -> lowest-index ties) ----
    mv_s[wv * 64 + lane] = minv;
    mi_s[wv * 64 + lane] = mini;
    __syncthreads();
    float bv = mv_s[lane];
    int   bk = mi_s[lane];
    #pragma unroll
    for (int w = 1; w < 4; ++w) {
        float v  = mv_s[w * 64 + lane];
        int   i2 = mi_s[w * 64 + lane];
        if (v < bv) { bv = v; bk = i2; }
    }
    if (wv == 0) idxf[t0 + lane] = (float)bk;

    // ---- gather winner rows (wave w covers dq 8w..8w+7), loss, overwrite zt ----
    float lsum = 0.0f;
    #pragma unroll
    for (int q = 0; q < 8; ++q) {
        int dq = wv * 8 + q;
        float4 cv = *(const float4*)(cb + (size_t)bk * DDIM + 4 * dq);  // L2 gather
        float4 zv = *(const float4*)(&zt[dq * PITCH + 4 * lane]);
        float dx = cv.x - zv.x, dy = cv.y - zv.y;
        float dzv = cv.z - zv.z, dw = cv.w - zv.w;
        lsum += dx * dx + dy * dy + dzv * dzv + dw * dw;
        *(float4*)(&zt[dq * PITCH + 4 * lane]) = cv;   // own range: no cross-wave hazard
    }
    #pragma unroll
    for (int off = 32; off > 0; off >>= 1) lsum += __shfl_down(lsum, off);
    if (lane == 0) atomicAdd(loss_accum, lsum);
    __syncthreads();

    // ---- coalesced z_q write-out ----
    #pragma unroll
    for (int it = 0; it < 8; ++it) {
        int g = it * 256 + tid;
        int r = g >> 5, d4 = g & 31;
        float4 v = *(const float4*)(&zt[d4 * PITCH + 4 * r]);
        *(float4*)(zq + (size_t)(t0 + r) * DDIM + 4 * d4) = v;
    }
}

__global__ void loss_final(const float* __restrict__ a, float* __restrict__ out) {
    if (threadIdx.x == 0)
        out[0] = (float)((double)a[0] * 1.25 / (double)((size_t)NTOK * DDIM));
}

extern "C" void kernel_launch(void* const* d_in, const int* in_sizes, int n_in,
                              void* d_out, int out_size, void* d_ws, size_t ws_size,
                              hipStream_t stream) {
    const float* z  = (const float*)d_in[0];   // [32768,128]
    const float* cb = (const float*)d_in[1];   // [1024,128]
    float* out  = (float*)d_out;
    float* zq   = out;                         // 4194304
    float* loss = out + (size_t)NTOK * DDIM;   // 1
    float* idxf = loss + 1;                    // 32768

    float* cnorm      = (float*)d_ws;          // 1024
    float* loss_accum = cnorm + KCODES;        // 1

    hipMemsetAsync(loss_accum, 0, sizeof(float), stream);
    cnorm_np<<<KCODES / 64, 64, 0, stream>>>(cb, cnorm);
    vq_main<<<NTOK / TPB_TOK, 256, 0, stream>>>(z, cb, cnorm, zq, idxf, loss_accum);
    loss_final<<<1, 64, 0, stream>>>(loss_accum, loss);
}

// Round 5
// 298.163 us; speedup vs baseline: 1.7210x; 1.7210x over previous
//
#include <hip/hip_runtime.h>
#include <float.h>

// Problem constants: B=32 L=1024 D=128 K=1024
#define NTOK 32768
#define DDIM 128
#define KCODES 1024
#define PZ 68           // zt pitch: multiple of 4 -> 16B-aligned ds_read_b128;
                        // staging stores are lane=token -> conflict-free any pitch

// Optimization barrier: blocks fma-contraction/reassociation so we replicate
// numpy's exact fp32 rounding sequence (argmin must match numpy bit-for-bit).
__device__ __forceinline__ float nofuse(float x) { asm volatile("" : "+v"(x)); return x; }

// ---------------- prep: cbT[d][k] transpose + cnorm (numpy pairwise) --------
// 32 blocks x 256 threads; block handles 32 codes. cb is 512KB total.
__global__ void prep_cb(const float* __restrict__ cb, float* __restrict__ cbT,
                        float* __restrict__ cnorm) {
    __shared__ float rows[32 * 129];
    const int tid = threadIdx.x;
    const int k0 = blockIdx.x * 32;
    // stage 32 rows, coalesced float4
    #pragma unroll
    for (int it = 0; it < 4; ++it) {
        int g = it * 256 + tid;          // 0..1023 float4
        int r = g >> 5, d4 = g & 31;
        float4 v = *(const float4*)(cb + (size_t)(k0 + r) * DDIM + 4 * d4);
        rows[r * 129 + 4 * d4 + 0] = v.x;
        rows[r * 129 + 4 * d4 + 1] = v.y;
        rows[r * 129 + 4 * d4 + 2] = v.z;
        rows[r * 129 + 4 * d4 + 3] = v.w;
    }
    __syncthreads();
    // transposed write: cbT[d][k0+4*c4+s] = rows[4*c4+s][d]
    #pragma unroll
    for (int it = 0; it < 4; ++it) {
        int h = it * 256 + tid;          // 0..1023
        int d = h >> 3, c4 = h & 7;      // d 0..127, 8 float4 cover 32 codes
        float4 v;
        v.x = rows[(4 * c4 + 0) * 129 + d];
        v.y = rows[(4 * c4 + 1) * 129 + d];
        v.z = rows[(4 * c4 + 2) * 129 + d];
        v.w = rows[(4 * c4 + 3) * 129 + d];
        *(float4*)(cbT + (size_t)d * KCODES + k0 + 4 * c4) = v;
    }
    // cnorm in exact numpy pairwise order
    if (tid < 32) {
        const float* p = &rows[tid * 129];
        float r[8];
        #pragma unroll
        for (int j = 0; j < 8; ++j) { float v = p[j]; r[j] = nofuse(v * v); }
        #pragma unroll
        for (int i = 8; i < DDIM; i += 8) {
            #pragma unroll
            for (int j = 0; j < 8; ++j) {
                float v = p[i + j];
                r[j] = nofuse(r[j] + nofuse(v * v));
            }
        }
        float s01 = nofuse(r[0] + r[1]);
        float s23 = nofuse(r[2] + r[3]);
        float s45 = nofuse(r[4] + r[5]);
        float s67 = nofuse(r[6] + r[7]);
        cnorm[k0 + tid] = nofuse(nofuse(s01 + s23) + nofuse(s45 + s67));
    }
}

// ---------------- distances + argmin: z from LDS, cbT streamed from L2 ------
// dist(t,k) = fl( fl(zn_t + cn_k) - 2*dot ), dot = fmaf chain d=0..127
// ascending — bit-identical to the R3 kernel that passed.
__global__ __launch_bounds__(256, 2)
void vq_dist(const float* __restrict__ z, const float* __restrict__ cbT,
             const float* __restrict__ cnorm,
             float* __restrict__ minv_out, int* __restrict__ mini_out) {
    __shared__ float zt[DDIM * PZ];      // [d][token], 34816 B
    __shared__ float zn_s[64];

    const int tid  = threadIdx.x;
    const int tx   = tid & 31;           // codes 8*tx..8*tx+7 per pass
    const int ty   = tid >> 5;           // tokens 8*ty..8*ty+7
    const int lane = tid & 63;
    const int wv   = tid >> 6;
    const int tile = blockIdx.x >> 1;
    const int half = blockIdx.x & 1;
    const int t0   = tile * 64;
    const int kb   = half * 512;

    // ---- stage zt transposed, lane = token -> conflict-free stores ----
    // wave wv covers d4 = 8*wv .. 8*wv+7; global reads are 16B/lane gathers of
    // 64 rows — L1/L2 line reuse across the 8 iterations covers the waste.
    #pragma unroll
    for (int q = 0; q < 8; ++q) {
        int d4 = wv * 8 + q;
        float4 v = *(const float4*)(z + (size_t)(t0 + lane) * DDIM + 4 * d4);
        zt[(4 * d4 + 0) * PZ + lane] = v.x;   // bank = lane%32 (+const): 2-way, free
        zt[(4 * d4 + 1) * PZ + lane] = v.y;
        zt[(4 * d4 + 2) * PZ + lane] = v.z;
        zt[(4 * d4 + 3) * PZ + lane] = v.w;
    }
    __syncthreads();

    // ---- zn for the 64 tokens (wave 0), exact numpy pairwise order ----
    if (tid < 64) {
        float rr[8];
        #pragma unroll
        for (int j = 0; j < 8; ++j) { float v = zt[j * PZ + tid]; rr[j] = nofuse(v * v); }
        #pragma unroll
        for (int i = 1; i < 16; ++i)
            #pragma unroll
            for (int j = 0; j < 8; ++j) {
                float v = zt[(8 * i + j) * PZ + tid];
                rr[j] = nofuse(rr[j] + nofuse(v * v));
            }
        float s01 = nofuse(rr[0] + rr[1]);
        float s23 = nofuse(rr[2] + rr[3]);
        float s45 = nofuse(rr[4] + rr[5]);
        float s67 = nofuse(rr[6] + rr[7]);
        zn_s[tid] = nofuse(nofuse(s01 + s23) + nofuse(s45 + s67));
    }
    __syncthreads();

    float minv[8];
    int   mini[8];
    #pragma unroll
    for (int i = 0; i < 8; ++i) { minv[i] = FLT_MAX; mini[i] = 0; }

    // ---- two passes of 256 codes: 8 tok x 8 code micro-tile ----
    for (int p = 0; p < 2; ++p) {
        const int kbp = kb + p * 256;
        const float* cp = cbT + kbp + 8 * tx;

        float acc[8][8];
        #pragma unroll
        for (int i = 0; i < 8; ++i)
            #pragma unroll
            for (int j = 0; j < 8; ++j) acc[i][j] = 0.0f;

        #pragma unroll 2
        for (int d = 0; d < DDIM; ++d) {
            // code side: coalesced 1KB/wave stream from L2-resident cbT (VMEM pipe)
            float4 c0 = *(const float4*)(cp + (size_t)d * KCODES);
            float4 c1 = *(const float4*)(cp + (size_t)d * KCODES + 4);
            // token side: broadcast LDS reads (2 distinct addrs/wave, conflict-free)
            float4 z0 = *(const float4*)(&zt[d * PZ + 8 * ty]);
            float4 z1 = *(const float4*)(&zt[d * PZ + 8 * ty + 4]);
            float zr[8] = {z0.x, z0.y, z0.z, z0.w, z1.x, z1.y, z1.z, z1.w};
            float cr[8] = {c0.x, c0.y, c0.z, c0.w, c1.x, c1.y, c1.z, c1.w};
            #pragma unroll
            for (int i = 0; i < 8; ++i)
                #pragma unroll
                for (int j = 0; j < 8; ++j)
                    acc[i][j] = fmaf(zr[i], cr[j], acc[i][j]);
        }

        float4 cn0 = *(const float4*)(cnorm + kbp + 8 * tx);
        float4 cn1 = *(const float4*)(cnorm + kbp + 8 * tx + 4);
        float cnr[8] = {cn0.x, cn0.y, cn0.z, cn0.w, cn1.x, cn1.y, cn1.z, cn1.w};
        #pragma unroll
        for (int j = 0; j < 8; ++j) {
            int code = kbp + 8 * tx + j;
            #pragma unroll
            for (int i = 0; i < 8; ++i) {
                float s = nofuse(zn_s[8 * ty + i] + cnr[j]);
                float dist = fmaf(-2.0f, acc[i][j], s);   // 2*acc exact (pow2)
                // j,p ascend -> per-thread codes ascend; strict < keeps lowest idx
                if (dist < minv[i]) { minv[i] = dist; mini[i] = code; }
            }
        }
    }

    // ---- block reduction over the 32 tx threads per token ----
    __syncthreads();                     // zt free — alias as reduction space
    float* rv = zt;                      // [64][32]
    int*   ri = (int*)(zt + 2048);       // [64][32]
    #pragma unroll
    for (int i = 0; i < 8; ++i) {
        rv[(8 * ty + i) * 32 + tx] = minv[i];
        ri[(8 * ty + i) * 32 + tx] = mini[i];
    }
    __syncthreads();
    if (tid < 64) {
        float bv = rv[tid * 32];
        int   bi = ri[tid * 32];
        #pragma unroll
        for (int j = 1; j < 32; ++j) {
            float v  = rv[tid * 32 + j];
            int   ii = ri[tid * 32 + j];
            if (v < bv || (v == bv && ii < bi)) { bv = v; bi = ii; }
        }
        minv_out[half * NTOK + t0 + tid] = bv;
        mini_out[half * NTOK + t0 + tid] = bi;
    }
}

// ---------------- merge halves + gather z_q + loss accumulation ------------
__global__ void gather_loss(const float* __restrict__ z, const float* __restrict__ cb,
                            const float* __restrict__ minv_part, const int* __restrict__ mini_part,
                            float* __restrict__ zq, float* __restrict__ idxf,
                            float* __restrict__ loss_accum) {
    int g = blockIdx.x * 256 + threadIdx.x;
    int token = g >> 5;
    int q4 = g & 31;
    float v0 = minv_part[token];
    float v1 = minv_part[NTOK + token];
    int   i0 = mini_part[token];
    int   i1 = mini_part[NTOK + token];
    int k = (v1 < v0) ? i1 : i0;   // tie -> half0 (lower index) — numpy argmin
    float4 q  = *(const float4*)(cb + (size_t)k * DDIM + 4 * q4);
    float4 zv = *(const float4*)(z + (size_t)token * DDIM + 4 * q4);
    *(float4*)(zq + (size_t)token * DDIM + 4 * q4) = q;
    if (q4 == 0) idxf[token] = (float)k;
    float dx = q.x - zv.x, dy = q.y - zv.y, dz = q.z - zv.z, dw = q.w - zv.w;
    float s = dx * dx + dy * dy + dz * dz + dw * dw;
    #pragma unroll
    for (int off = 32; off > 0; off >>= 1) s += __shfl_down(s, off);
    __shared__ float sm[4];
    int lane = threadIdx.x & 63, wv = threadIdx.x >> 6;
    if (lane == 0) sm[wv] = s;
    __syncthreads();
    if (threadIdx.x == 0) atomicAdd(loss_accum, sm[0] + sm[1] + sm[2] + sm[3]);
}

__global__ void loss_final(const float* __restrict__ a, float* __restrict__ out) {
    if (threadIdx.x == 0)
        out[0] = (float)((double)a[0] * 1.25 / (double)((size_t)NTOK * DDIM));
}

extern "C" void kernel_launch(void* const* d_in, const int* in_sizes, int n_in,
                              void* d_out, int out_size, void* d_ws, size_t ws_size,
                              hipStream_t stream) {
    const float* z  = (const float*)d_in[0];   // [32768,128]
    const float* cb = (const float*)d_in[1];   // [1024,128]
    float* out  = (float*)d_out;
    float* zq   = out;                         // 4194304
    float* loss = out + (size_t)NTOK * DDIM;   // 1
    float* idxf = loss + 1;                    // 32768

    float* cbT        = (float*)d_ws;                    // 128*1024 = 512KB
    float* cnorm      = cbT + (size_t)DDIM * KCODES;     // 1024
    float* minv_part  = cnorm + KCODES;                  // 2*32768
    int*   mini_part  = (int*)(minv_part + 2 * NTOK);    // 2*32768
    float* loss_accum = (float*)(mini_part + 2 * NTOK);  // 1

    hipMemsetAsync(loss_accum, 0, sizeof(float), stream);
    prep_cb<<<KCODES / 32, 256, 0, stream>>>(cb, cbT, cnorm);
    vq_dist<<<1024, 256, 0, stream>>>(z, cbT, cnorm, minv_part, mini_part);
    gather_loss<<<NTOK * 32 / 256, 256, 0, stream>>>(z, cb, minv_part, mini_part,
                                                     zq, idxf, loss_accum);
    loss_final<<<1, 64, 0, stream>>>(loss_accum, loss);
}